// Round 15
// baseline (200.514 us; speedup 1.0000x reference)
//
#include <hip/hip_runtime.h>

#define N_NODES 100000
#define DIM     128
#define HID     256
#define BN_EPS  1e-5f
#define BK_BITS 9
#define NBK     196
#define BKCAP   12288
#define EPB     4096
#define CVT_BLOCKS 3125       // 3.2M float4 / 1024 per block (512 thr x 2)
#define WPREP_BLOCKS 16       // 65536 halfs / (512 thr x 8)

typedef _Float16     half8  __attribute__((ext_vector_type(8)));
typedef float        f32x4  __attribute__((ext_vector_type(4)));

static __device__ __forceinline__ f32x4 mfma16h(half8 a, half8 b, f32x4 c) {
    return __builtin_amdgcn_mfma_f32_16x16x32_f16(a, b, c, 0, 0, 0);
}

// ---------------- Binning pass 1 ----------------
__global__ __launch_bounds__(256) void binscatter_kernel(
    const int* __restrict__ src, const int* __restrict__ dst,
    int* __restrict__ cursor, unsigned int* __restrict__ pairs, int nE) {
    __shared__ int cnt[NBK];
    __shared__ int gbase[NBK];
    int t = threadIdx.x;
    for (int i = t; i < NBK; i += 256) cnt[i] = 0;
    __syncthreads();
    int e0 = blockIdx.x * EPB;
    int n = min(EPB, nE - e0);
    int d[16];
#pragma unroll
    for (int k = 0; k < 16; ++k) {
        int idx = t + k * 256;
        if (idx < n) {
            d[k] = dst[e0 + idx];
            atomicAdd(&cnt[d[k] >> BK_BITS], 1);
        }
    }
    __syncthreads();
    for (int i = t; i < NBK; i += 256) {
        int c = cnt[i];
        gbase[i] = c ? atomicAdd(&cursor[i], c) : 0;
    }
    __syncthreads();
    for (int i = t; i < NBK; i += 256) cnt[i] = 0;
    __syncthreads();
#pragma unroll
    for (int k = 0; k < 16; ++k) {
        int idx = t + k * 256;
        if (idx < n) {
            int b = d[k] >> BK_BITS;
            int r = atomicAdd(&cnt[b], 1);
            pairs[(long long)b * BKCAP + gbase[b] + r] =
                ((unsigned)src[e0 + idx] << BK_BITS) | ((unsigned)d[k] & 511u);
        }
    }
}

// ---------------- Fused: bucket_fill (0..NBK-1) + cvt (NBK..) + W-prep (last 16) ----------------
__global__ __launch_bounds__(512) void fill_cvt_kernel(
    const unsigned int* __restrict__ pairs, const int* __restrict__ cursor,
    int* __restrict__ rowptr, int* __restrict__ csr_src,
    const float* __restrict__ x, _Float16* __restrict__ x16,
    const float* __restrict__ W1, const float* __restrict__ W2,
    _Float16* __restrict__ W1T, _Float16* __restrict__ W2T) {
    int t = threadIdx.x;
    if (blockIdx.x >= NBK + CVT_BLOCKS) {
        // ---- W prep: transpose + fp16 convert, half8 coalesced stores ----
        int bc = blockIdx.x - NBK - CVT_BLOCKS;     // 0..15
        int o0 = (bc & 7) * 4096 + t * 8;           // half index within matrix
        if (bc < 8) {                               // W1T[col][k] = W1[k][col], 256x128
            int col = o0 >> 7, k0 = o0 & 127;
            half8 v;
#pragma unroll
            for (int i = 0; i < 8; ++i) v[i] = (_Float16)W1[(k0 + i) * HID + col];
            *(half8*)&W1T[o0] = v;
        } else {                                    // W2T[col][k] = W2[k][col], 128x256
            int col = o0 >> 8, k0 = o0 & 255;
            half8 v;
#pragma unroll
            for (int i = 0; i < 8; ++i) v[i] = (_Float16)W2[(k0 + i) * DIM + col];
            *(half8*)&W2T[o0] = v;
        }
        return;
    }
    if (blockIdx.x >= NBK) {
        // ---- cvt: x -> fp16, 2 float4 per thread ----
        int bc = blockIdx.x - NBK;
#pragma unroll
        for (int k = 0; k < 2; ++k) {
            int i = bc * 1024 + k * 512 + t;
            float4 v = ((const float4*)x)[i];
            _Float16 h0 = (_Float16)v.x, h1 = (_Float16)v.y,
                     h2 = (_Float16)v.z, h3 = (_Float16)v.w;
            unsigned long long pk =
                (unsigned long long)__builtin_bit_cast(unsigned short, h0)
              | ((unsigned long long)__builtin_bit_cast(unsigned short, h1) << 16)
              | ((unsigned long long)__builtin_bit_cast(unsigned short, h2) << 32)
              | ((unsigned long long)__builtin_bit_cast(unsigned short, h3) << 48);
            ((unsigned long long*)x16)[i] = pk;
        }
        return;
    }
    // ---- bucket fill (bscan folded in) ----
    __shared__ int cnt[512];
    __shared__ int off[512];
    __shared__ int stmp[256];
    __shared__ int s_base;
    int b = blockIdx.x;
    if (t < 256) stmp[t] = (t < NBK) ? cursor[t] : 0;
    __syncthreads();
    for (int s = 1; s < 256; s <<= 1) {
        int a = (t >= s && t < 256) ? stmp[t - s] : 0;
        __syncthreads();
        if (t < 256) stmp[t] += a;
        __syncthreads();
    }
    if (t == 0) s_base = stmp[b] - cursor[b];
    __syncthreads();
    int base = s_base;
    int m = cursor[b];
    int nd0 = b << BK_BITS;
    int nn = min(512, N_NODES - nd0);
    const unsigned int* bp = pairs + (long long)b * BKCAP;
    cnt[t] = 0;
    __syncthreads();
    for (int e = t; e < m; e += 512)
        atomicAdd(&cnt[bp[e] & 511u], 1);
    __syncthreads();
    int v = cnt[t];
    off[t] = v;
    __syncthreads();
    for (int s = 1; s < 512; s <<= 1) {
        int a = (t >= s) ? off[t - s] : 0;
        __syncthreads();
        off[t] += a;
        __syncthreads();
    }
    int excl = off[t] - v;
    __syncthreads();
    off[t] = excl;
    if (t < nn) rowptr[nd0 + t] = base + excl;
    if (b == NBK - 1 && t == 0) rowptr[N_NODES] = base + m;
    cnt[t] = 0;
    __syncthreads();
    for (int e = t; e < m; e += 512) {
        unsigned int p = bp[e];
        int li = p & 511u;
        int r = atomicAdd(&cnt[li], 1);
        csr_src[base + off[li] + r] = (int)(p >> BK_BITS);
    }
}

// ---------------- Fused gather + MLP: one block per 16 nodes ----------------
// Phase A: 4 waves, each gathers 4 nodes (r12 loop) into swizzled LDS tile shh.
// Phase B: GEMM1 (B streamed from W1T) -> sh1 -> GEMM2 (W2T) -> out.
__global__ __launch_bounds__(256, 3) void gin_fused_kernel(
    const _Float16* __restrict__ x16, const float* __restrict__ epsp,
    const int* __restrict__ rowptr, const int* __restrict__ csr_src,
    const _Float16* __restrict__ W1T, const _Float16* __restrict__ W2T,
    const float* __restrict__ b1, const float* __restrict__ g1,
    const float* __restrict__ be1, const float* __restrict__ m1,
    const float* __restrict__ v1,
    const float* __restrict__ b2, const float* __restrict__ g2,
    const float* __restrict__ be2, const float* __restrict__ m2,
    const float* __restrict__ v2,
    float* __restrict__ out) {
    __shared__ _Float16 shh[16 * DIM];   // 4 KB, XOR-swizzled (8-half granules)
    __shared__ _Float16 sh1[16 * HID];   // 8 KB, XOR-swizzled
    int t = threadIdx.x;
    int w = t >> 6, lane = t & 63;
    int g = lane >> 4, part = lane & 15;
    int node0 = blockIdx.x * 16;
    const half8* xp = (const half8*)x16;
    float sc = 1.f + epsp[0];

    // ---- Phase A: gather 16 nodes into shh ----
    for (int it = 0; it < 4; ++it) {
        int ln = 4 * w + it;
        int node = node0 + ln;
        int beg = rowptr[node], end = rowptr[node + 1];
        float s[8] = {0,0,0,0,0,0,0,0};
        int j = beg;
        for (; j + 8 <= end; j += 8) {
            int n0 = csr_src[j + g];
            int n1 = csr_src[j + 4 + g];
            half8 v0 = xp[n0 * 16 + part];
            half8 v1 = xp[n1 * 16 + part];
#pragma unroll
            for (int i = 0; i < 8; ++i) s[i] += (float)v0[i] + (float)v1[i];
        }
        int r = end - j;
        if (g < r) {
            half8 v = xp[csr_src[j + g] * 16 + part];
#pragma unroll
            for (int i = 0; i < 8; ++i) s[i] += (float)v[i];
        }
        if (g + 4 < r) {
            half8 v = xp[csr_src[j + 4 + g] * 16 + part];
#pragma unroll
            for (int i = 0; i < 8; ++i) s[i] += (float)v[i];
        }
#pragma unroll
        for (int i = 0; i < 8; ++i) {
            s[i] += __shfl_xor(s[i], 16);
            s[i] += __shfl_xor(s[i], 32);
        }
        if (lane < 16) {
            half8 xv = xp[node * 16 + part];
            half8 o;
#pragma unroll
            for (int i = 0; i < 8; ++i) o[i] = (_Float16)fmaf(sc, (float)xv[i], s[i]);
            *(half8*)&shh[ln * DIM + ((part * 8) ^ ((ln & 7) << 3))] = o;
        }
    }
    __syncthreads();

    // ---- Phase B: MLP. wave w = col-group cg ----
    int cg = w, l15 = lane & 15, q = lane >> 4;
    half8 A[4];
    {
        int sx = (l15 & 7) << 3;
#pragma unroll
        for (int ks = 0; ks < 4; ++ks)
            A[ks] = *(const half8*)&shh[l15 * DIM + ((32 * ks + 8 * q) ^ sx)];
    }
    f32x4 acc[4];
#pragma unroll
    for (int nt = 0; nt < 4; ++nt) acc[nt] = (f32x4)(0.f);
#pragma unroll
    for (int nt = 0; nt < 4; ++nt) {
        int col = 64 * cg + 16 * nt + l15;
        const half8* bp = (const half8*)&W1T[col * DIM + 8 * q];
#pragma unroll
        for (int ks = 0; ks < 4; ++ks)
            acc[nt] = mfma16h(A[ks], bp[ks * 4], acc[nt]);
    }
#pragma unroll
    for (int nt = 0; nt < 4; ++nt) {
        int col = 64 * cg + 16 * nt + l15;
        float s1 = g1[col] * rsqrtf(v1[col] + BN_EPS);
        float f1 = (b1[col] - m1[col]) * s1 + be1[col];
#pragma unroll
        for (int reg = 0; reg < 4; ++reg) {
            int row = 4 * q + reg;
            float vv = fmaxf(0.f, fmaf(acc[nt][reg], s1, f1));
            sh1[row * HID + (col ^ ((row & 7) << 3))] = (_Float16)vv;
        }
    }
    __syncthreads();
    half8 A2[8];
    {
        int sx = (l15 & 7) << 3;
#pragma unroll
        for (int ks = 0; ks < 8; ++ks)
            A2[ks] = *(const half8*)&sh1[l15 * HID + ((32 * ks + 8 * q) ^ sx)];
    }
    f32x4 acc2[2];
    acc2[0] = (f32x4)(0.f); acc2[1] = (f32x4)(0.f);
#pragma unroll
    for (int nt = 0; nt < 2; ++nt) {
        int col = 32 * cg + 16 * nt + l15;
        const half8* bp = (const half8*)&W2T[col * HID + 8 * q];
#pragma unroll
        for (int ks = 0; ks < 8; ++ks)
            acc2[nt] = mfma16h(A2[ks], bp[ks * 4], acc2[nt]);
    }
#pragma unroll
    for (int nt = 0; nt < 2; ++nt) {
        int col = 32 * cg + 16 * nt + l15;
        float s2 = g2[col] * rsqrtf(v2[col] + BN_EPS);
        float f2 = (b2[col] - m2[col]) * s2 + be2[col];
#pragma unroll
        for (int reg = 0; reg < 4; ++reg) {
            int orow = node0 + 4 * q + reg;
            out[(long long)orow * DIM + col] = fmaxf(0.f, fmaf(acc2[nt][reg], s2, f2));
        }
    }
}

extern "C" void kernel_launch(void* const* d_in, const int* in_sizes, int n_in,
                              void* d_out, int out_size, void* d_ws, size_t ws_size,
                              hipStream_t stream) {
    const float* x   = (const float*)d_in[0];
    const float* eps = (const float*)d_in[1];
    const float* W1  = (const float*)d_in[2];
    const float* b1  = (const float*)d_in[3];
    const float* g1  = (const float*)d_in[4];
    const float* be1 = (const float*)d_in[5];
    const float* m1  = (const float*)d_in[6];
    const float* v1  = (const float*)d_in[7];
    const float* W2  = (const float*)d_in[8];
    const float* b2  = (const float*)d_in[9];
    const float* g2  = (const float*)d_in[10];
    const float* be2 = (const float*)d_in[11];
    const float* m2  = (const float*)d_in[12];
    const float* v2  = (const float*)d_in[13];
    const int*   ei  = (const int*)d_in[14];
    int nE = in_sizes[14] / 2;
    const int* src = ei;
    const int* dst = ei + nE;

    char* ws = (char*)d_ws;
    int*          cursor  = (int*)(ws + 0);                 // NBK ints
    int*          rowptr  = (int*)(ws + 4096);              // (N+1) ints -> 404,100
    int*          csr_src = (int*)(ws + 405504);            // nE ints -> 6,805,504
    unsigned int* pairs   = (unsigned int*)(ws + 6806528);  // 9.63MB -> 16,440,320
    _Float16*     x16     = (_Float16*)(ws + 16441344);     // 25.6MB -> 42,041,344
    _Float16*     W1T     = (_Float16*)(ws + 42041344);     // 64KB -> 42,106,880
    _Float16*     W2T     = (_Float16*)(ws + 42106880);     // 64KB -> 42,172,416

    // 1) binning pass 1
    hipMemsetAsync(cursor, 0, NBK * sizeof(int), stream);
    binscatter_kernel<<<(nE + EPB - 1) / EPB, 256, 0, stream>>>(src, dst, cursor, pairs, nE);

    // 2) fill + cvt + W-prep fused
    fill_cvt_kernel<<<NBK + CVT_BLOCKS + WPREP_BLOCKS, 512, 0, stream>>>(
        pairs, cursor, rowptr, csr_src, x, x16, W1, W2, W1T, W2T);

    // 3) fused gather + MLP -> out
    gin_fused_kernel<<<N_NODES / 16, 256, 0, stream>>>(
        x16, eps, rowptr, csr_src, W1T, W2T,
        b1, g1, be1, m1, v1, b2, g2, be2, m2, v2, (float*)d_out);
}

// Round 16
// 162.287 us; speedup vs baseline: 1.2355x; 1.2355x over previous
//
#include <hip/hip_runtime.h>

#define N_NODES 100000
#define DIM     128
#define HID     256
#define BN_EPS  1e-5f
#define TILES16 6250          // N_NODES / 16
#define MLP_GRID 1024
#define BK_BITS 9
#define NBK     196
#define BKCAP   11264
#define EPB     2048
#define CVT_BLOCKS 3125       // 3.2M float4 / 1024 per block (512 thr x 2)
#define WPREP_BLOCKS 16

typedef _Float16     half8  __attribute__((ext_vector_type(8)));
typedef float        f32x4  __attribute__((ext_vector_type(4)));

static __device__ __forceinline__ f32x4 mfma16h(half8 a, half8 b, f32x4 c) {
    return __builtin_amdgcn_mfma_f32_16x16x32_f16(a, b, c, 0, 0, 0);
}

// ---------------- Binning pass 1 ----------------
__global__ __launch_bounds__(256) void binscatter_kernel(
    const int* __restrict__ src, const int* __restrict__ dst,
    int* __restrict__ cursor, unsigned int* __restrict__ pairs, int nE) {
    __shared__ int cnt[NBK];
    __shared__ int gbase[NBK];
    int t = threadIdx.x;
    for (int i = t; i < NBK; i += 256) cnt[i] = 0;
    __syncthreads();
    int e0 = blockIdx.x * EPB;
    int n = min(EPB, nE - e0);
    int d[8];
#pragma unroll
    for (int k = 0; k < 8; ++k) {
        int idx = t + k * 256;
        if (idx < n) {
            d[k] = dst[e0 + idx];
            atomicAdd(&cnt[d[k] >> BK_BITS], 1);
        }
    }
    __syncthreads();
    for (int i = t; i < NBK; i += 256) {
        int c = cnt[i];
        gbase[i] = c ? atomicAdd(&cursor[i], c) : 0;
    }
    __syncthreads();
    for (int i = t; i < NBK; i += 256) cnt[i] = 0;
    __syncthreads();
#pragma unroll
    for (int k = 0; k < 8; ++k) {
        int idx = t + k * 256;
        if (idx < n) {
            int b = d[k] >> BK_BITS;
            int r = atomicAdd(&cnt[b], 1);
            pairs[(long long)b * BKCAP + gbase[b] + r] =
                ((unsigned)src[e0 + idx] << BK_BITS) | ((unsigned)d[k] & 511u);
        }
    }
}

// ---------------- Fused: bucket_fill (0..NBK-1) + cvt (NBK..) + W-prep (last 16) ----------------
__global__ __launch_bounds__(512) void fill_cvt_kernel(
    const unsigned int* __restrict__ pairs, const int* __restrict__ cursor,
    int* __restrict__ rowptr, int* __restrict__ csr_src,
    const float* __restrict__ x, _Float16* __restrict__ x16,
    const float* __restrict__ W1, const float* __restrict__ W2,
    _Float16* __restrict__ W1T, _Float16* __restrict__ W2T) {
    int t = threadIdx.x;
    if (blockIdx.x >= NBK + CVT_BLOCKS) {
        // ---- W prep: transpose + fp16 convert, half8 coalesced stores ----
        int bc = blockIdx.x - NBK - CVT_BLOCKS;     // 0..15
        int o0 = (bc & 7) * 4096 + t * 8;
        if (bc < 8) {                               // W1T[col][k] = W1[k][col], 256x128
            int col = o0 >> 7, k0 = o0 & 127;
            half8 v;
#pragma unroll
            for (int i = 0; i < 8; ++i) v[i] = (_Float16)W1[(k0 + i) * HID + col];
            *(half8*)&W1T[o0] = v;
        } else {                                    // W2T[col][k] = W2[k][col], 128x256
            int col = o0 >> 8, k0 = o0 & 255;
            half8 v;
#pragma unroll
            for (int i = 0; i < 8; ++i) v[i] = (_Float16)W2[(k0 + i) * DIM + col];
            *(half8*)&W2T[o0] = v;
        }
        return;
    }
    if (blockIdx.x >= NBK) {
        // ---- cvt: x -> fp16, 2 float4 per thread ----
        int bc = blockIdx.x - NBK;
#pragma unroll
        for (int k = 0; k < 2; ++k) {
            int i = bc * 1024 + k * 512 + t;
            float4 v = ((const float4*)x)[i];
            _Float16 h0 = (_Float16)v.x, h1 = (_Float16)v.y,
                     h2 = (_Float16)v.z, h3 = (_Float16)v.w;
            unsigned long long pk =
                (unsigned long long)__builtin_bit_cast(unsigned short, h0)
              | ((unsigned long long)__builtin_bit_cast(unsigned short, h1) << 16)
              | ((unsigned long long)__builtin_bit_cast(unsigned short, h2) << 32)
              | ((unsigned long long)__builtin_bit_cast(unsigned short, h3) << 48);
            ((unsigned long long*)x16)[i] = pk;
        }
        return;
    }
    // ---- bucket fill (bscan folded in) ----
    __shared__ int cnt[512];
    __shared__ int off[512];
    __shared__ int stmp[256];
    __shared__ int s_base;
    int b = blockIdx.x;
    if (t < 256) stmp[t] = (t < NBK) ? cursor[t] : 0;
    __syncthreads();
    for (int s = 1; s < 256; s <<= 1) {
        int a = (t >= s && t < 256) ? stmp[t - s] : 0;
        __syncthreads();
        if (t < 256) stmp[t] += a;
        __syncthreads();
    }
    if (t == 0) s_base = stmp[b] - cursor[b];
    __syncthreads();
    int base = s_base;
    int m = cursor[b];
    int nd0 = b << BK_BITS;
    int nn = min(512, N_NODES - nd0);
    const unsigned int* bp = pairs + (long long)b * BKCAP;
    cnt[t] = 0;
    __syncthreads();
    for (int e = t; e < m; e += 512)
        atomicAdd(&cnt[bp[e] & 511u], 1);
    __syncthreads();
    int v = cnt[t];
    off[t] = v;
    __syncthreads();
    for (int s = 1; s < 512; s <<= 1) {
        int a = (t >= s) ? off[t - s] : 0;
        __syncthreads();
        off[t] += a;
        __syncthreads();
    }
    int excl = off[t] - v;
    __syncthreads();
    off[t] = excl;
    if (t < nn) rowptr[nd0 + t] = base + excl;
    if (b == NBK - 1 && t == 0) rowptr[N_NODES] = base + m;
    cnt[t] = 0;
    __syncthreads();
    for (int e = t; e < m; e += 512) {
        unsigned int p = bp[e];
        int li = p & 511u;
        int r = atomicAdd(&cnt[li], 1);
        csr_src[base + off[li] + r] = (int)(p >> BK_BITS);
    }
}

// ---------------- Gather-sum (r12 form): one wave per node, 4 edges x 16 lanes ----------------
__global__ __launch_bounds__(256) void gather_kernel(
    const _Float16* __restrict__ x16, const float* __restrict__ epsp,
    const int* __restrict__ rowptr, const int* __restrict__ csr_src,
    _Float16* __restrict__ h16) {
    int node = blockIdx.x * 4 + (threadIdx.x >> 6);
    int lane = threadIdx.x & 63;
    int g = lane >> 4;
    int part = lane & 15;
    const half8* xp = (const half8*)x16;
    int beg = rowptr[node], end = rowptr[node + 1];
    float s[8] = {0,0,0,0,0,0,0,0};
    int j = beg;
    for (; j + 8 <= end; j += 8) {
        int n0 = csr_src[j + g];
        int n1 = csr_src[j + 4 + g];
        half8 v0 = xp[n0 * 16 + part];
        half8 v1 = xp[n1 * 16 + part];
#pragma unroll
        for (int i = 0; i < 8; ++i) s[i] += (float)v0[i] + (float)v1[i];
    }
    int r = end - j;
    if (g < r) {
        half8 v = xp[csr_src[j + g] * 16 + part];
#pragma unroll
        for (int i = 0; i < 8; ++i) s[i] += (float)v[i];
    }
    if (g + 4 < r) {
        half8 v = xp[csr_src[j + 4 + g] * 16 + part];
#pragma unroll
        for (int i = 0; i < 8; ++i) s[i] += (float)v[i];
    }
#pragma unroll
    for (int i = 0; i < 8; ++i) {
        s[i] += __shfl_xor(s[i], 16);
        s[i] += __shfl_xor(s[i], 32);
    }
    if (lane < 16) {
        float sc = 1.f + epsp[0];
        half8 xv = xp[node * 16 + part];
        half8 o;
#pragma unroll
        for (int i = 0; i < 8; ++i) o[i] = (_Float16)fmaf(sc, (float)xv[i], s[i]);
        ((half8*)h16)[node * 16 + part] = o;
    }
}

// ---------------- Fused MLP: 256 thr / 16-row tiles, fp16 weight prologue ----------------
__global__ __launch_bounds__(256, 2) void mlp_fused_kernel(
    const _Float16* __restrict__ h16,
    const _Float16* __restrict__ W1T, const _Float16* __restrict__ W2T,
    const float* __restrict__ b1, const float* __restrict__ g1,
    const float* __restrict__ be1, const float* __restrict__ m1,
    const float* __restrict__ v1,
    const float* __restrict__ b2, const float* __restrict__ g2,
    const float* __restrict__ be2, const float* __restrict__ m2,
    const float* __restrict__ v2,
    float* __restrict__ out) {
    __shared__ _Float16 sh1[16 * HID];   // 8 KB, XOR-swizzled
    int t = threadIdx.x;
    int cg = t >> 6, l = t & 63;
    int l15 = l & 15, q = l >> 4;

    half8 B1[4][4];
    float s1v[4], sh1v[4];
#pragma unroll
    for (int nt = 0; nt < 4; ++nt) {
        int col = 64 * cg + 16 * nt + l15;
#pragma unroll
        for (int ks = 0; ks < 4; ++ks)
            B1[nt][ks] = *(const half8*)&W1T[col * DIM + 32 * ks + 8 * q];
        float sc = g1[col] * rsqrtf(v1[col] + BN_EPS);
        s1v[nt] = sc;
        sh1v[nt] = (b1[col] - m1[col]) * sc + be1[col];
    }
    half8 B2[2][8];
    float s2v[2], sh2v[2];
#pragma unroll
    for (int nt = 0; nt < 2; ++nt) {
        int col = 32 * cg + 16 * nt + l15;
#pragma unroll
        for (int ks = 0; ks < 8; ++ks)
            B2[nt][ks] = *(const half8*)&W2T[col * HID + 32 * ks + 8 * q];
        float sc = g2[col] * rsqrtf(v2[col] + BN_EPS);
        s2v[nt] = sc;
        sh2v[nt] = (b2[col] - m2[col]) * sc + be2[col];
    }

    for (int tile = blockIdx.x; tile < TILES16; tile += MLP_GRID) {
        int row0 = tile * 16;
        const _Float16* arow = h16 + (long long)(row0 + l15) * DIM;
        half8 A[4];
#pragma unroll
        for (int ks = 0; ks < 4; ++ks) A[ks] = *(const half8*)(arow + 32 * ks + 8 * q);
        f32x4 acc[4];
#pragma unroll
        for (int nt = 0; nt < 4; ++nt) acc[nt] = (f32x4)(0.f);
#pragma unroll
        for (int nt = 0; nt < 4; ++nt)
#pragma unroll
            for (int ks = 0; ks < 4; ++ks)
                acc[nt] = mfma16h(A[ks], B1[nt][ks], acc[nt]);
#pragma unroll
        for (int nt = 0; nt < 4; ++nt) {
            int col = 64 * cg + 16 * nt + l15;
#pragma unroll
            for (int reg = 0; reg < 4; ++reg) {
                int row = 4 * q + reg;
                float vv = fmaxf(0.f, fmaf(acc[nt][reg], s1v[nt], sh1v[nt]));
                sh1[row * HID + (col ^ ((row & 7) << 3))] = (_Float16)vv;
            }
        }
        __syncthreads();
        half8 A2[8];
        {
            int row = l15;
            int sx = (row & 7) << 3;
#pragma unroll
            for (int ks = 0; ks < 8; ++ks)
                A2[ks] = *(const half8*)&sh1[row * HID + ((32 * ks + 8 * q) ^ sx)];
        }
        __syncthreads();
        f32x4 acc2[2];
        acc2[0] = (f32x4)(0.f); acc2[1] = (f32x4)(0.f);
#pragma unroll
        for (int nt = 0; nt < 2; ++nt)
#pragma unroll
            for (int ks = 0; ks < 8; ++ks)
                acc2[nt] = mfma16h(A2[ks], B2[nt][ks], acc2[nt]);
#pragma unroll
        for (int nt = 0; nt < 2; ++nt) {
            int col = 32 * cg + 16 * nt + l15;
#pragma unroll
            for (int reg = 0; reg < 4; ++reg) {
                int orow = row0 + 4 * q + reg;
                out[(long long)orow * DIM + col] =
                    fmaxf(0.f, fmaf(acc2[nt][reg], s2v[nt], sh2v[nt]));
            }
        }
    }
}

extern "C" void kernel_launch(void* const* d_in, const int* in_sizes, int n_in,
                              void* d_out, int out_size, void* d_ws, size_t ws_size,
                              hipStream_t stream) {
    const float* x   = (const float*)d_in[0];
    const float* eps = (const float*)d_in[1];
    const float* W1  = (const float*)d_in[2];
    const float* b1  = (const float*)d_in[3];
    const float* g1  = (const float*)d_in[4];
    const float* be1 = (const float*)d_in[5];
    const float* m1  = (const float*)d_in[6];
    const float* v1  = (const float*)d_in[7];
    const float* W2  = (const float*)d_in[8];
    const float* b2  = (const float*)d_in[9];
    const float* g2  = (const float*)d_in[10];
    const float* be2 = (const float*)d_in[11];
    const float* m2  = (const float*)d_in[12];
    const float* v2  = (const float*)d_in[13];
    const int*   ei  = (const int*)d_in[14];
    int nE = in_sizes[14] / 2;
    const int* src = ei;
    const int* dst = ei + nE;

    // ws layout (total 66.97MB, under the proven 67.65MB footprint):
    char* ws = (char*)d_ws;
    int*          cursor  = (int*)(ws + 0);                 // NBK ints
    int*          rowptr  = (int*)(ws + 4096);              // (N+1) ints -> 404,100
    int*          csr_src = (int*)(ws + 405504);            // nE ints -> 6,805,504
    unsigned int* pairs   = (unsigned int*)(ws + 6806528);  // 196*11264*4 -> 15,637,504
    _Float16*     x16     = (_Float16*)(ws + 15638528);     // 25.6MB -> 41,238,528
    _Float16*     W1T     = (_Float16*)(ws + 41238528);     // 64KB -> 41,304,064
    _Float16*     W2T     = (_Float16*)(ws + 41304064);     // 64KB -> 41,369,600
    _Float16*     h16     = (_Float16*)(ws + 41369600);     // 25.6MB -> 66,969,600

    // 1) binning pass 1
    hipMemsetAsync(cursor, 0, NBK * sizeof(int), stream);
    binscatter_kernel<<<(nE + EPB - 1) / EPB, 256, 0, stream>>>(src, dst, cursor, pairs, nE);

    // 2) fill + cvt + W-prep fused
    fill_cvt_kernel<<<NBK + CVT_BLOCKS + WPREP_BLOCKS, 512, 0, stream>>>(
        pairs, cursor, rowptr, csr_src, x, x16, W1, W2, W1T, W2T);

    // 3) gather-sum -> h16 (one wave per node)
    gather_kernel<<<N_NODES / 4, 256, 0, stream>>>(x16, eps, rowptr, csr_src, h16);

    // 4) fused MLP -> out (fp32)
    mlp_fused_kernel<<<MLP_GRID, 256, 0, stream>>>(h16, W1T, W2T,
                                                   b1, g1, be1, m1, v1,
                                                   b2, g2, be2, m2, v2, (float*)d_out);
}

// Round 18
// 149.933 us; speedup vs baseline: 1.3374x; 1.0824x over previous
//
#include <hip/hip_runtime.h>

#define N_NODES 100000
#define DIM     128
#define HID     256
#define BN_EPS  1e-5f
#define TILES16 6250          // N_NODES / 16
#define MLP_GRID 512
#define BK_BITS 9
#define NBK     196
#define BKCAP   11264
#define EPB     4096
#define CVT_BLOCKS 3125       // 3.2M float4 / 1024 per block (512 thr x 2)
#define WPREP_BLOCKS 16

typedef _Float16     half8  __attribute__((ext_vector_type(8)));
typedef float        f32x4  __attribute__((ext_vector_type(4)));

static __device__ __forceinline__ f32x4 mfma16h(half8 a, half8 b, f32x4 c) {
    return __builtin_amdgcn_mfma_f32_16x16x32_f16(a, b, c, 0, 0, 0);
}

// ---------------- Binning pass 1 (r12 config: EPB=4096) ----------------
__global__ __launch_bounds__(256) void binscatter_kernel(
    const int* __restrict__ src, const int* __restrict__ dst,
    int* __restrict__ cursor, unsigned int* __restrict__ pairs, int nE) {
    __shared__ int cnt[NBK];
    __shared__ int gbase[NBK];
    int t = threadIdx.x;
    for (int i = t; i < NBK; i += 256) cnt[i] = 0;
    __syncthreads();
    int e0 = blockIdx.x * EPB;
    int n = min(EPB, nE - e0);
    int d[16];
#pragma unroll
    for (int k = 0; k < 16; ++k) {
        int idx = t + k * 256;
        if (idx < n) {
            d[k] = dst[e0 + idx];
            atomicAdd(&cnt[d[k] >> BK_BITS], 1);
        }
    }
    __syncthreads();
    for (int i = t; i < NBK; i += 256) {
        int c = cnt[i];
        gbase[i] = c ? atomicAdd(&cursor[i], c) : 0;
    }
    __syncthreads();
    for (int i = t; i < NBK; i += 256) cnt[i] = 0;
    __syncthreads();
#pragma unroll
    for (int k = 0; k < 16; ++k) {
        int idx = t + k * 256;
        if (idx < n) {
            int b = d[k] >> BK_BITS;
            int r = atomicAdd(&cnt[b], 1);
            pairs[(long long)b * BKCAP + gbase[b] + r] =
                ((unsigned)src[e0 + idx] << BK_BITS) | ((unsigned)d[k] & 511u);
        }
    }
}

// ---------------- Fused: bucket_fill (0..NBK-1) + cvt (NBK..) + W-prep (last 16) ----------------
__global__ __launch_bounds__(512) void fill_cvt_kernel(
    const unsigned int* __restrict__ pairs, const int* __restrict__ cursor,
    int* __restrict__ rowptr, int* __restrict__ csr_src,
    const float* __restrict__ x, _Float16* __restrict__ x16,
    const float* __restrict__ W1, const float* __restrict__ W2,
    _Float16* __restrict__ W1T, _Float16* __restrict__ W2T) {
    int t = threadIdx.x;
    if (blockIdx.x >= NBK + CVT_BLOCKS) {
        // ---- W prep: transpose + fp16 convert, half8 coalesced stores ----
        int bc = blockIdx.x - NBK - CVT_BLOCKS;     // 0..15
        int o0 = (bc & 7) * 4096 + t * 8;
        if (bc < 8) {                               // W1T[col][k] = W1[k][col], 256x128
            int col = o0 >> 7, k0 = o0 & 127;
            half8 v;
#pragma unroll
            for (int i = 0; i < 8; ++i) v[i] = (_Float16)W1[(k0 + i) * HID + col];
            *(half8*)&W1T[o0] = v;
        } else {                                    // W2T[col][k] = W2[k][col], 128x256
            int col = o0 >> 8, k0 = o0 & 255;
            half8 v;
#pragma unroll
            for (int i = 0; i < 8; ++i) v[i] = (_Float16)W2[(k0 + i) * DIM + col];
            *(half8*)&W2T[o0] = v;
        }
        return;
    }
    if (blockIdx.x >= NBK) {
        // ---- cvt: x -> fp16, 2 float4 per thread ----
        int bc = blockIdx.x - NBK;
#pragma unroll
        for (int k = 0; k < 2; ++k) {
            int i = bc * 1024 + k * 512 + t;
            float4 v = ((const float4*)x)[i];
            _Float16 h0 = (_Float16)v.x, h1 = (_Float16)v.y,
                     h2 = (_Float16)v.z, h3 = (_Float16)v.w;
            unsigned long long pk =
                (unsigned long long)__builtin_bit_cast(unsigned short, h0)
              | ((unsigned long long)__builtin_bit_cast(unsigned short, h1) << 16)
              | ((unsigned long long)__builtin_bit_cast(unsigned short, h2) << 32)
              | ((unsigned long long)__builtin_bit_cast(unsigned short, h3) << 48);
            ((unsigned long long*)x16)[i] = pk;
        }
        return;
    }
    // ---- bucket fill (bscan folded in) ----
    __shared__ int cnt[512];
    __shared__ int off[512];
    __shared__ int stmp[256];
    __shared__ int s_base;
    int b = blockIdx.x;
    if (t < 256) stmp[t] = (t < NBK) ? cursor[t] : 0;
    __syncthreads();
    for (int s = 1; s < 256; s <<= 1) {
        int a = (t >= s && t < 256) ? stmp[t - s] : 0;
        __syncthreads();
        if (t < 256) stmp[t] += a;
        __syncthreads();
    }
    if (t == 0) s_base = stmp[b] - cursor[b];
    __syncthreads();
    int base = s_base;
    int m = cursor[b];
    int nd0 = b << BK_BITS;
    int nn = min(512, N_NODES - nd0);
    const unsigned int* bp = pairs + (long long)b * BKCAP;
    cnt[t] = 0;
    __syncthreads();
    for (int e = t; e < m; e += 512)
        atomicAdd(&cnt[bp[e] & 511u], 1);
    __syncthreads();
    int v = cnt[t];
    off[t] = v;
    __syncthreads();
    for (int s = 1; s < 512; s <<= 1) {
        int a = (t >= s) ? off[t - s] : 0;
        __syncthreads();
        off[t] += a;
        __syncthreads();
    }
    int excl = off[t] - v;
    __syncthreads();
    off[t] = excl;
    if (t < nn) rowptr[nd0 + t] = base + excl;
    if (b == NBK - 1 && t == 0) rowptr[N_NODES] = base + m;
    cnt[t] = 0;
    __syncthreads();
    for (int e = t; e < m; e += 512) {
        unsigned int p = bp[e];
        int li = p & 511u;
        int r = atomicAdd(&cnt[li], 1);
        csr_src[base + off[li] + r] = (int)(p >> BK_BITS);
    }
}

// ---------------- Gather-sum (r12 form): one wave per node, 4 edges x 16 lanes ----------------
__global__ __launch_bounds__(256) void gather_kernel(
    const _Float16* __restrict__ x16, const float* __restrict__ epsp,
    const int* __restrict__ rowptr, const int* __restrict__ csr_src,
    _Float16* __restrict__ h16) {
    int node = blockIdx.x * 4 + (threadIdx.x >> 6);
    int lane = threadIdx.x & 63;
    int g = lane >> 4;
    int part = lane & 15;
    const half8* xp = (const half8*)x16;
    int beg = rowptr[node], end = rowptr[node + 1];
    float s[8] = {0,0,0,0,0,0,0,0};
    int j = beg;
    for (; j + 8 <= end; j += 8) {
        int n0 = csr_src[j + g];
        int n1 = csr_src[j + 4 + g];
        half8 v0 = xp[n0 * 16 + part];
        half8 v1 = xp[n1 * 16 + part];
#pragma unroll
        for (int i = 0; i < 8; ++i) s[i] += (float)v0[i] + (float)v1[i];
    }
    int r = end - j;
    if (g < r) {
        half8 v = xp[csr_src[j + g] * 16 + part];
#pragma unroll
        for (int i = 0; i < 8; ++i) s[i] += (float)v[i];
    }
    if (g + 4 < r) {
        half8 v = xp[csr_src[j + 4 + g] * 16 + part];
#pragma unroll
        for (int i = 0; i < 8; ++i) s[i] += (float)v[i];
    }
#pragma unroll
    for (int i = 0; i < 8; ++i) {
        s[i] += __shfl_xor(s[i], 16);
        s[i] += __shfl_xor(s[i], 32);
    }
    if (lane < 16) {
        float sc = 1.f + epsp[0];
        half8 xv = xp[node * 16 + part];
        half8 o;
#pragma unroll
        for (int i = 0; i < 8; ++i) o[i] = (_Float16)fmaf(sc, (float)xv[i], s[i]);
        ((half8*)h16)[node * 16 + part] = o;
    }
}

// ---------------- Fused MLP: 256 thr / 16-row tiles, fp16 weight prologue, grid 512 ----------------
__global__ __launch_bounds__(256, 2) void mlp_fused_kernel(
    const _Float16* __restrict__ h16,
    const _Float16* __restrict__ W1T, const _Float16* __restrict__ W2T,
    const float* __restrict__ b1, const float* __restrict__ g1,
    const float* __restrict__ be1, const float* __restrict__ m1,
    const float* __restrict__ v1,
    const float* __restrict__ b2, const float* __restrict__ g2,
    const float* __restrict__ be2, const float* __restrict__ m2,
    const float* __restrict__ v2,
    float* __restrict__ out) {
    __shared__ _Float16 sh1[16 * HID];   // 8 KB, XOR-swizzled
    int t = threadIdx.x;
    int cg = t >> 6, l = t & 63;
    int l15 = l & 15, q = l >> 4;

    half8 B1[4][4];
    float s1v[4], sh1v[4];
#pragma unroll
    for (int nt = 0; nt < 4; ++nt) {
        int col = 64 * cg + 16 * nt + l15;
#pragma unroll
        for (int ks = 0; ks < 4; ++ks)
            B1[nt][ks] = *(const half8*)&W1T[col * DIM + 32 * ks + 8 * q];
        float sc = g1[col] * rsqrtf(v1[col] + BN_EPS);
        s1v[nt] = sc;
        sh1v[nt] = (b1[col] - m1[col]) * sc + be1[col];
    }
    half8 B2[2][8];
    float s2v[2], sh2v[2];
#pragma unroll
    for (int nt = 0; nt < 2; ++nt) {
        int col = 32 * cg + 16 * nt + l15;
#pragma unroll
        for (int ks = 0; ks < 8; ++ks)
            B2[nt][ks] = *(const half8*)&W2T[col * HID + 32 * ks + 8 * q];
        float sc = g2[col] * rsqrtf(v2[col] + BN_EPS);
        s2v[nt] = sc;
        sh2v[nt] = (b2[col] - m2[col]) * sc + be2[col];
    }

    for (int tile = blockIdx.x; tile < TILES16; tile += MLP_GRID) {
        int row0 = tile * 16;
        const _Float16* arow = h16 + (long long)(row0 + l15) * DIM;
        half8 A[4];
#pragma unroll
        for (int ks = 0; ks < 4; ++ks) A[ks] = *(const half8*)(arow + 32 * ks + 8 * q);
        f32x4 acc[4];
#pragma unroll
        for (int nt = 0; nt < 4; ++nt) acc[nt] = (f32x4)(0.f);
#pragma unroll
        for (int nt = 0; nt < 4; ++nt)
#pragma unroll
            for (int ks = 0; ks < 4; ++ks)
                acc[nt] = mfma16h(A[ks], B1[nt][ks], acc[nt]);
#pragma unroll
        for (int nt = 0; nt < 4; ++nt) {
            int col = 64 * cg + 16 * nt + l15;
#pragma unroll
            for (int reg = 0; reg < 4; ++reg) {
                int row = 4 * q + reg;
                float vv = fmaxf(0.f, fmaf(acc[nt][reg], s1v[nt], sh1v[nt]));
                sh1[row * HID + (col ^ ((row & 7) << 3))] = (_Float16)vv;
            }
        }
        __syncthreads();
        half8 A2[8];
        {
            int row = l15;
            int sx = (row & 7) << 3;
#pragma unroll
            for (int ks = 0; ks < 8; ++ks)
                A2[ks] = *(const half8*)&sh1[row * HID + ((32 * ks + 8 * q) ^ sx)];
        }
        __syncthreads();
        f32x4 acc2[2];
        acc2[0] = (f32x4)(0.f); acc2[1] = (f32x4)(0.f);
#pragma unroll
        for (int nt = 0; nt < 2; ++nt)
#pragma unroll
            for (int ks = 0; ks < 8; ++ks)
                acc2[nt] = mfma16h(A2[ks], B2[nt][ks], acc2[nt]);
#pragma unroll
        for (int nt = 0; nt < 2; ++nt) {
            int col = 32 * cg + 16 * nt + l15;
#pragma unroll
            for (int reg = 0; reg < 4; ++reg) {
                int orow = row0 + 4 * q + reg;
                out[(long long)orow * DIM + col] =
                    fmaxf(0.f, fmaf(acc2[nt][reg], s2v[nt], sh2v[nt]));
            }
        }
    }
}

extern "C" void kernel_launch(void* const* d_in, const int* in_sizes, int n_in,
                              void* d_out, int out_size, void* d_ws, size_t ws_size,
                              hipStream_t stream) {
    const float* x   = (const float*)d_in[0];
    const float* eps = (const float*)d_in[1];
    const float* W1  = (const float*)d_in[2];
    const float* b1  = (const float*)d_in[3];
    const float* g1  = (const float*)d_in[4];
    const float* be1 = (const float*)d_in[5];
    const float* m1  = (const float*)d_in[6];
    const float* v1  = (const float*)d_in[7];
    const float* W2  = (const float*)d_in[8];
    const float* b2  = (const float*)d_in[9];
    const float* g2  = (const float*)d_in[10];
    const float* be2 = (const float*)d_in[11];
    const float* m2  = (const float*)d_in[12];
    const float* v2  = (const float*)d_in[13];
    const int*   ei  = (const int*)d_in[14];
    int nE = in_sizes[14] / 2;
    const int* src = ei;
    const int* dst = ei + nE;

    char* ws = (char*)d_ws;
    int*          cursor  = (int*)(ws + 0);                 // NBK ints
    int*          rowptr  = (int*)(ws + 4096);              // (N+1) ints -> 404,100
    int*          csr_src = (int*)(ws + 405504);            // nE ints -> 6,805,504
    unsigned int* pairs   = (unsigned int*)(ws + 6806528);  // 196*11264*4 -> 15,637,504
    _Float16*     x16     = (_Float16*)(ws + 15638528);     // 25.6MB -> 41,238,528
    _Float16*     W1T     = (_Float16*)(ws + 41238528);     // 64KB -> 41,304,064
    _Float16*     W2T     = (_Float16*)(ws + 41304064);     // 64KB -> 41,369,600
    _Float16*     h16     = (_Float16*)(ws + 41369600);     // 25.6MB -> 66,969,600

    // 1) binning pass 1
    hipMemsetAsync(cursor, 0, NBK * sizeof(int), stream);
    binscatter_kernel<<<(nE + EPB - 1) / EPB, 256, 0, stream>>>(src, dst, cursor, pairs, nE);

    // 2) fill + cvt + W-prep fused
    fill_cvt_kernel<<<NBK + CVT_BLOCKS + WPREP_BLOCKS, 512, 0, stream>>>(
        pairs, cursor, rowptr, csr_src, x, x16, W1, W2, W1T, W2T);

    // 3) gather-sum -> h16 (one wave per node)
    gather_kernel<<<N_NODES / 4, 256, 0, stream>>>(x16, eps, rowptr, csr_src, h16);

    // 4) fused MLP -> out (fp32)
    mlp_fused_kernel<<<MLP_GRID, 256, 0, stream>>>(h16, W1T, W2T,
                                                   b1, g1, be1, m1, v1,
                                                   b2, g2, be2, m2, v2, (float*)d_out);
}

// Round 19
// 147.710 us; speedup vs baseline: 1.3575x; 1.0150x over previous
//
#include <hip/hip_runtime.h>

#define N_NODES 100000
#define DIM     128
#define HID     256
#define BN_EPS  1e-5f
#define TILES16 6250          // N_NODES / 16
#define MLP_GRID 512
#define BK_BITS 9
#define NBK     196
#define BKCAP   11264
#define EPB     4096
#define CVT_BLOCKS 3125       // 3.2M float4 / 1024 per block (512 thr x 2)
#define WPREP_BLOCKS 16

typedef _Float16     half8  __attribute__((ext_vector_type(8)));
typedef float        f32x4  __attribute__((ext_vector_type(4)));

static __device__ __forceinline__ f32x4 mfma16h(half8 a, half8 b, f32x4 c) {
    return __builtin_amdgcn_mfma_f32_16x16x32_f16(a, b, c, 0, 0, 0);
}

// ---------------- Binning pass 1: LDS-staged, coalesced pair writes ----------------
__global__ __launch_bounds__(256) void binscatter_kernel(
    const int* __restrict__ src, const int* __restrict__ dst,
    int* __restrict__ cursor, unsigned int* __restrict__ pairs, int nE) {
    __shared__ int cnt[NBK];
    __shared__ int lofs[256];              // scan workspace -> exclusive offsets
    __shared__ int gbase[NBK];
    __shared__ unsigned int staged[EPB];   // 16 KB bucket-sorted edges
    __shared__ unsigned char sbk[EPB];     // 4 KB bucket id per slot
    int t = threadIdx.x;
    for (int i = t; i < NBK; i += 256) cnt[i] = 0;
    __syncthreads();
    int e0 = blockIdx.x * EPB;
    int n = min(EPB, nE - e0);
    int d[16];
    // pass 1: count
#pragma unroll
    for (int k = 0; k < 16; ++k) {
        int idx = t + k * 256;
        if (idx < n) {
            d[k] = dst[e0 + idx];
            atomicAdd(&cnt[d[k] >> BK_BITS], 1);
        }
    }
    __syncthreads();
    // claim global chunks + local exclusive scan of cnt
    for (int i = t; i < NBK; i += 256) {
        int c = cnt[i];
        gbase[i] = c ? atomicAdd(&cursor[i], c) : 0;
    }
    lofs[t] = (t < NBK) ? cnt[t] : 0;
    __syncthreads();
    for (int s = 1; s < 256; s <<= 1) {
        int a = (t >= s) ? lofs[t - s] : 0;
        __syncthreads();
        lofs[t] += a;
        __syncthreads();
    }
    if (t < NBK) lofs[t] -= cnt[t];        // inclusive -> exclusive
    __syncthreads();
    for (int i = t; i < NBK; i += 256) cnt[i] = 0;   // reuse as local cursor
    __syncthreads();
    // pass 2: place into LDS staging (bucket-sorted)
#pragma unroll
    for (int k = 0; k < 16; ++k) {
        int idx = t + k * 256;
        if (idx < n) {
            int b = d[k] >> BK_BITS;
            int r = atomicAdd(&cnt[b], 1);
            int slot = lofs[b] + r;
            staged[slot] = ((unsigned)src[e0 + idx] << BK_BITS) | ((unsigned)d[k] & 511u);
            sbk[slot] = (unsigned char)b;
        }
    }
    __syncthreads();
    // pass 3: coalesced write (consecutive slots -> consecutive global addrs per bucket run)
    for (int i = t; i < n; i += 256) {
        int b = sbk[i];
        int r = i - lofs[b];
        pairs[(long long)b * BKCAP + gbase[b] + r] = staged[i];
    }
}

// ---------------- Fused: bucket_fill (0..NBK-1) + cvt (NBK..) + W-prep (last 16) ----------------
__global__ __launch_bounds__(512) void fill_cvt_kernel(
    const unsigned int* __restrict__ pairs, const int* __restrict__ cursor,
    int* __restrict__ rowptr, int* __restrict__ csr_src,
    const float* __restrict__ x, _Float16* __restrict__ x16,
    const float* __restrict__ W1, const float* __restrict__ W2,
    _Float16* __restrict__ W1T, _Float16* __restrict__ W2T) {
    int t = threadIdx.x;
    if (blockIdx.x >= NBK + CVT_BLOCKS) {
        // ---- W prep: transpose + fp16 convert, half8 coalesced stores ----
        int bc = blockIdx.x - NBK - CVT_BLOCKS;     // 0..15
        int o0 = (bc & 7) * 4096 + t * 8;
        if (bc < 8) {                               // W1T[col][k] = W1[k][col], 256x128
            int col = o0 >> 7, k0 = o0 & 127;
            half8 v;
#pragma unroll
            for (int i = 0; i < 8; ++i) v[i] = (_Float16)W1[(k0 + i) * HID + col];
            *(half8*)&W1T[o0] = v;
        } else {                                    // W2T[col][k] = W2[k][col], 128x256
            int col = o0 >> 8, k0 = o0 & 255;
            half8 v;
#pragma unroll
            for (int i = 0; i < 8; ++i) v[i] = (_Float16)W2[(k0 + i) * DIM + col];
            *(half8*)&W2T[o0] = v;
        }
        return;
    }
    if (blockIdx.x >= NBK) {
        // ---- cvt: x -> fp16, 2 float4 per thread ----
        int bc = blockIdx.x - NBK;
#pragma unroll
        for (int k = 0; k < 2; ++k) {
            int i = bc * 1024 + k * 512 + t;
            float4 v = ((const float4*)x)[i];
            _Float16 h0 = (_Float16)v.x, h1 = (_Float16)v.y,
                     h2 = (_Float16)v.z, h3 = (_Float16)v.w;
            unsigned long long pk =
                (unsigned long long)__builtin_bit_cast(unsigned short, h0)
              | ((unsigned long long)__builtin_bit_cast(unsigned short, h1) << 16)
              | ((unsigned long long)__builtin_bit_cast(unsigned short, h2) << 32)
              | ((unsigned long long)__builtin_bit_cast(unsigned short, h3) << 48);
            ((unsigned long long*)x16)[i] = pk;
        }
        return;
    }
    // ---- bucket fill (bscan folded in) ----
    __shared__ int cnt[512];
    __shared__ int off[512];
    __shared__ int stmp[256];
    __shared__ int s_base;
    int b = blockIdx.x;
    if (t < 256) stmp[t] = (t < NBK) ? cursor[t] : 0;
    __syncthreads();
    for (int s = 1; s < 256; s <<= 1) {
        int a = (t >= s && t < 256) ? stmp[t - s] : 0;
        __syncthreads();
        if (t < 256) stmp[t] += a;
        __syncthreads();
    }
    if (t == 0) s_base = stmp[b] - cursor[b];
    __syncthreads();
    int base = s_base;
    int m = cursor[b];
    int nd0 = b << BK_BITS;
    int nn = min(512, N_NODES - nd0);
    const unsigned int* bp = pairs + (long long)b * BKCAP;
    cnt[t] = 0;
    __syncthreads();
    for (int e = t; e < m; e += 512)
        atomicAdd(&cnt[bp[e] & 511u], 1);
    __syncthreads();
    int v = cnt[t];
    off[t] = v;
    __syncthreads();
    for (int s = 1; s < 512; s <<= 1) {
        int a = (t >= s) ? off[t - s] : 0;
        __syncthreads();
        off[t] += a;
        __syncthreads();
    }
    int excl = off[t] - v;
    __syncthreads();
    off[t] = excl;
    if (t < nn) rowptr[nd0 + t] = base + excl;
    if (b == NBK - 1 && t == 0) rowptr[N_NODES] = base + m;
    cnt[t] = 0;
    __syncthreads();
    for (int e = t; e < m; e += 512) {
        unsigned int p = bp[e];
        int li = p & 511u;
        int r = atomicAdd(&cnt[li], 1);
        csr_src[base + off[li] + r] = (int)(p >> BK_BITS);
    }
}

// ---------------- Gather-sum (r12 form): one wave per node, 4 edges x 16 lanes ----------------
__global__ __launch_bounds__(256) void gather_kernel(
    const _Float16* __restrict__ x16, const float* __restrict__ epsp,
    const int* __restrict__ rowptr, const int* __restrict__ csr_src,
    _Float16* __restrict__ h16) {
    int node = blockIdx.x * 4 + (threadIdx.x >> 6);
    int lane = threadIdx.x & 63;
    int g = lane >> 4;
    int part = lane & 15;
    const half8* xp = (const half8*)x16;
    int beg = rowptr[node], end = rowptr[node + 1];
    float s[8] = {0,0,0,0,0,0,0,0};
    int j = beg;
    for (; j + 8 <= end; j += 8) {
        int n0 = csr_src[j + g];
        int n1 = csr_src[j + 4 + g];
        half8 v0 = xp[n0 * 16 + part];
        half8 v1 = xp[n1 * 16 + part];
#pragma unroll
        for (int i = 0; i < 8; ++i) s[i] += (float)v0[i] + (float)v1[i];
    }
    int r = end - j;
    if (g < r) {
        half8 v = xp[csr_src[j + g] * 16 + part];
#pragma unroll
        for (int i = 0; i < 8; ++i) s[i] += (float)v[i];
    }
    if (g + 4 < r) {
        half8 v = xp[csr_src[j + 4 + g] * 16 + part];
#pragma unroll
        for (int i = 0; i < 8; ++i) s[i] += (float)v[i];
    }
#pragma unroll
    for (int i = 0; i < 8; ++i) {
        s[i] += __shfl_xor(s[i], 16);
        s[i] += __shfl_xor(s[i], 32);
    }
    if (lane < 16) {
        float sc = 1.f + epsp[0];
        half8 xv = xp[node * 16 + part];
        half8 o;
#pragma unroll
        for (int i = 0; i < 8; ++i) o[i] = (_Float16)fmaf(sc, (float)xv[i], s[i]);
        ((half8*)h16)[node * 16 + part] = o;
    }
}

// ---------------- Fused MLP: 256 thr / 16-row tiles, fp16 weight prologue, grid 512 ----------------
__global__ __launch_bounds__(256, 2) void mlp_fused_kernel(
    const _Float16* __restrict__ h16,
    const _Float16* __restrict__ W1T, const _Float16* __restrict__ W2T,
    const float* __restrict__ b1, const float* __restrict__ g1,
    const float* __restrict__ be1, const float* __restrict__ m1,
    const float* __restrict__ v1,
    const float* __restrict__ b2, const float* __restrict__ g2,
    const float* __restrict__ be2, const float* __restrict__ m2,
    const float* __restrict__ v2,
    float* __restrict__ out) {
    __shared__ _Float16 sh1[16 * HID];   // 8 KB, XOR-swizzled
    int t = threadIdx.x;
    int cg = t >> 6, l = t & 63;
    int l15 = l & 15, q = l >> 4;

    half8 B1[4][4];
    float s1v[4], sh1v[4];
#pragma unroll
    for (int nt = 0; nt < 4; ++nt) {
        int col = 64 * cg + 16 * nt + l15;
#pragma unroll
        for (int ks = 0; ks < 4; ++ks)
            B1[nt][ks] = *(const half8*)&W1T[col * DIM + 32 * ks + 8 * q];
        float sc = g1[col] * rsqrtf(v1[col] + BN_EPS);
        s1v[nt] = sc;
        sh1v[nt] = (b1[col] - m1[col]) * sc + be1[col];
    }
    half8 B2[2][8];
    float s2v[2], sh2v[2];
#pragma unroll
    for (int nt = 0; nt < 2; ++nt) {
        int col = 32 * cg + 16 * nt + l15;
#pragma unroll
        for (int ks = 0; ks < 8; ++ks)
            B2[nt][ks] = *(const half8*)&W2T[col * HID + 32 * ks + 8 * q];
        float sc = g2[col] * rsqrtf(v2[col] + BN_EPS);
        s2v[nt] = sc;
        sh2v[nt] = (b2[col] - m2[col]) * sc + be2[col];
    }

    for (int tile = blockIdx.x; tile < TILES16; tile += MLP_GRID) {
        int row0 = tile * 16;
        const _Float16* arow = h16 + (long long)(row0 + l15) * DIM;
        half8 A[4];
#pragma unroll
        for (int ks = 0; ks < 4; ++ks) A[ks] = *(const half8*)(arow + 32 * ks + 8 * q);
        f32x4 acc[4];
#pragma unroll
        for (int nt = 0; nt < 4; ++nt) acc[nt] = (f32x4)(0.f);
#pragma unroll
        for (int nt = 0; nt < 4; ++nt)
#pragma unroll
            for (int ks = 0; ks < 4; ++ks)
                acc[nt] = mfma16h(A[ks], B1[nt][ks], acc[nt]);
#pragma unroll
        for (int nt = 0; nt < 4; ++nt) {
            int col = 64 * cg + 16 * nt + l15;
#pragma unroll
            for (int reg = 0; reg < 4; ++reg) {
                int row = 4 * q + reg;
                float vv = fmaxf(0.f, fmaf(acc[nt][reg], s1v[nt], sh1v[nt]));
                sh1[row * HID + (col ^ ((row & 7) << 3))] = (_Float16)vv;
            }
        }
        __syncthreads();
        half8 A2[8];
        {
            int row = l15;
            int sx = (row & 7) << 3;
#pragma unroll
            for (int ks = 0; ks < 8; ++ks)
                A2[ks] = *(const half8*)&sh1[row * HID + ((32 * ks + 8 * q) ^ sx)];
        }
        __syncthreads();
        f32x4 acc2[2];
        acc2[0] = (f32x4)(0.f); acc2[1] = (f32x4)(0.f);
#pragma unroll
        for (int nt = 0; nt < 2; ++nt)
#pragma unroll
            for (int ks = 0; ks < 8; ++ks)
                acc2[nt] = mfma16h(A2[ks], B2[nt][ks], acc2[nt]);
#pragma unroll
        for (int nt = 0; nt < 2; ++nt) {
            int col = 32 * cg + 16 * nt + l15;
#pragma unroll
            for (int reg = 0; reg < 4; ++reg) {
                int orow = row0 + 4 * q + reg;
                out[(long long)orow * DIM + col] =
                    fmaxf(0.f, fmaf(acc2[nt][reg], s2v[nt], sh2v[nt]));
            }
        }
    }
}

extern "C" void kernel_launch(void* const* d_in, const int* in_sizes, int n_in,
                              void* d_out, int out_size, void* d_ws, size_t ws_size,
                              hipStream_t stream) {
    const float* x   = (const float*)d_in[0];
    const float* eps = (const float*)d_in[1];
    const float* W1  = (const float*)d_in[2];
    const float* b1  = (const float*)d_in[3];
    const float* g1  = (const float*)d_in[4];
    const float* be1 = (const float*)d_in[5];
    const float* m1  = (const float*)d_in[6];
    const float* v1  = (const float*)d_in[7];
    const float* W2  = (const float*)d_in[8];
    const float* b2  = (const float*)d_in[9];
    const float* g2  = (const float*)d_in[10];
    const float* be2 = (const float*)d_in[11];
    const float* m2  = (const float*)d_in[12];
    const float* v2  = (const float*)d_in[13];
    const int*   ei  = (const int*)d_in[14];
    int nE = in_sizes[14] / 2;
    const int* src = ei;
    const int* dst = ei + nE;

    char* ws = (char*)d_ws;
    int*          cursor  = (int*)(ws + 0);                 // NBK ints
    int*          rowptr  = (int*)(ws + 4096);              // (N+1) ints -> 404,100
    int*          csr_src = (int*)(ws + 405504);            // nE ints -> 6,805,504
    unsigned int* pairs   = (unsigned int*)(ws + 6806528);  // 196*11264*4 -> 15,637,504
    _Float16*     x16     = (_Float16*)(ws + 15638528);     // 25.6MB -> 41,238,528
    _Float16*     W1T     = (_Float16*)(ws + 41238528);     // 64KB -> 41,304,064
    _Float16*     W2T     = (_Float16*)(ws + 41304064);     // 64KB -> 41,369,600
    _Float16*     h16     = (_Float16*)(ws + 41369600);     // 25.6MB -> 66,969,600

    // 1) binning pass 1 (LDS-staged coalesced writes)
    hipMemsetAsync(cursor, 0, NBK * sizeof(int), stream);
    binscatter_kernel<<<(nE + EPB - 1) / EPB, 256, 0, stream>>>(src, dst, cursor, pairs, nE);

    // 2) fill + cvt + W-prep fused
    fill_cvt_kernel<<<NBK + CVT_BLOCKS + WPREP_BLOCKS, 512, 0, stream>>>(
        pairs, cursor, rowptr, csr_src, x, x16, W1, W2, W1T, W2T);

    // 3) gather-sum -> h16 (one wave per node)
    gather_kernel<<<N_NODES / 4, 256, 0, stream>>>(x16, eps, rowptr, csr_src, h16);

    // 4) fused MLP -> out (fp32)
    mlp_fused_kernel<<<MLP_GRID, 256, 0, stream>>>(h16, W1T, W2T,
                                                   b1, g1, be1, m1, v1,
                                                   b2, g2, be2, m2, v2, (float*)d_out);
}